// Round 2
// baseline (355.569 us; speedup 1.0000x reference)
//
#include <hip/hip_runtime.h>
#include <hip/hip_bf16.h>
#include <math.h>

#define NN 6144
#define DD 128
#define NCLS 20
#define NBATCH 5

// ws float layout:
// [0,N)        rinv
// [N,2N)       rowPosT
// [2N,3N)      rowTotT
// [3N,4N)      rowPosB
// [4N,5N)      rowTotB
// [5N,5N+20)   lsum_t
// [5N+20,+40)  cnt_t
// [5N+40,+45)  lsum_b
// [5N+45,+50)  cnt_b
// [5N+50,+70)  classCnt (int)
// [5N+70,+170) pairCnt  (int)

__global__ __launch_bounds__(256) void k_init(float* __restrict__ ws) {
    int idx = blockIdx.x * 256 + threadIdx.x;
    int cnt = 4 * NN + 170;
    if (idx < cnt) ws[NN + idx] = 0.0f;
}

__global__ __launch_bounds__(256) void k_prep(const float* __restrict__ x,
                                              const int* __restrict__ tg,
                                              const int* __restrict__ bt,
                                              float* __restrict__ ws) {
    int lane = threadIdx.x & 63;
    int row  = blockIdx.x * 4 + (threadIdx.x >> 6);
    float a = x[row * DD + lane];
    float b = x[row * DD + 64 + lane];
    float s = a * a + b * b;
#pragma unroll
    for (int off = 32; off > 0; off >>= 1) s += __shfl_down(s, off, 64);
    if (lane == 0) {
        ws[row] = 1.0f / fmaxf(sqrtf(s), 1e-8f);
        int* ip = (int*)(ws + 5 * NN + 50);
        atomicAdd(&ip[tg[row]], 1);
        atomicAdd(&ip[NCLS + tg[row] * NBATCH + bt[row]], 1);
    }
}

// Block: 256 threads. Tile: 64 rows (i) x 128 cols (j). Per-thread: 4 rows x (4+4) cols.
// tx = t&15 -> cols {4tx..4tx+3} and {64+4tx..64+4tx+3}; ty = t>>4 -> rows 4ty..4ty+3.
__global__ __launch_bounds__(256) void k_main(const float* __restrict__ x,
                                              const float* __restrict__ temp,
                                              const int* __restrict__ tg,
                                              const int* __restrict__ bt,
                                              float* __restrict__ ws) {
    __shared__ float At[64][68];    // [k-local][row]  17,408 B
    __shared__ float Bt[64][132];   // [k-local][col]  33,792 B
    __shared__ float rjs[128];
    __shared__ int   tjs[128];
    __shared__ int   bjs[128];
    __shared__ float ris[64];
    __shared__ int   tis[64];
    __shared__ int   bis[64];

    const float* rinv   = ws;
    float* rowPosT = ws + NN;
    float* rowTotT = ws + 2 * NN;
    float* rowPosB = ws + 3 * NN;
    float* rowTotB = ws + 4 * NN;

    const int t  = threadIdx.x;
    const int tx = t & 15;
    const int ty = t >> 4;
    const int i0 = blockIdx.x * 64;
    const int jb = blockIdx.y * 768;

    const float tc = fminf(fmaxf(temp[0], 0.1f), 1.0f);
    const float L2E = 1.4426950408889634f;
    const float c1 = L2E / tc;       // exp(sim/t)  = 2^(sim*c1)
    const float c2 = 2.0f * L2E;     // exp(sim/.5) = 2^(sim*c2)

    if (t < 64) { ris[t] = rinv[i0 + t]; tis[t] = tg[i0 + t]; bis[t] = bt[i0 + t]; }
    __syncthreads();

    float ri[4]; int tir[4], bir[4];
#pragma unroll
    for (int r = 0; r < 4; ++r) {
        ri[r]  = ris[4 * ty + r];
        tir[r] = tis[4 * ty + r];
        bir[r] = bis[4 * ty + r];
    }

    float aPT[4] = {0, 0, 0, 0}, aTT[4] = {0, 0, 0, 0};
    float aPB[4] = {0, 0, 0, 0}, aTB[4] = {0, 0, 0, 0};

    for (int jt = 0; jt < 6; ++jt) {
        const int j0 = jb + jt * 128;
        __syncthreads();  // previous epilogue readers of rjs/tjs/bjs are done
        if (t < 128) { rjs[t] = rinv[j0 + t]; tjs[t] = tg[j0 + t]; bjs[t] = bt[j0 + t]; }

        float s0[4][4] = {{0}}, s1[4][4] = {{0}};

        for (int kc = 0; kc < 2; ++kc) {
            // stage A chunk: 64 rows x 64 k, transposed [k][row]
            {
                int row = t >> 2, kb = t & 3;
                const float* src = x + (i0 + row) * DD + kc * 64;
#pragma unroll
                for (int it = 0; it < 4; ++it) {
                    int k4 = kb + 4 * it;
                    float4 v = *(const float4*)(src + 4 * k4);
                    At[4 * k4 + 0][row] = v.x;
                    At[4 * k4 + 1][row] = v.y;
                    At[4 * k4 + 2][row] = v.z;
                    At[4 * k4 + 3][row] = v.w;
                }
            }
            // stage B chunk: 128 cols x 64 k, transposed [k][col]
            {
                int row = t >> 1, kb = t & 1;
                const float* src = x + (j0 + row) * DD + kc * 64;
#pragma unroll
                for (int it = 0; it < 8; ++it) {
                    int k4 = kb + 2 * it;
                    float4 v = *(const float4*)(src + 4 * k4);
                    Bt[4 * k4 + 0][row] = v.x;
                    Bt[4 * k4 + 1][row] = v.y;
                    Bt[4 * k4 + 2][row] = v.z;
                    Bt[4 * k4 + 3][row] = v.w;
                }
            }
            __syncthreads();

#pragma unroll 8
            for (int k = 0; k < 64; ++k) {
                float4 a4 = *(const float4*)&At[k][4 * ty];
                float4 b4 = *(const float4*)&Bt[k][4 * tx];
                float4 c4 = *(const float4*)&Bt[k][64 + 4 * tx];
                float av[4] = {a4.x, a4.y, a4.z, a4.w};
                float bv[4] = {b4.x, b4.y, b4.z, b4.w};
                float cv[4] = {c4.x, c4.y, c4.z, c4.w};
#pragma unroll
                for (int r = 0; r < 4; ++r) {
#pragma unroll
                    for (int c = 0; c < 4; ++c) {
                        s0[r][c] += av[r] * bv[c];
                        s1[r][c] += av[r] * cv[c];
                    }
                }
            }
            __syncthreads();
        }

        // epilogue: exp + masked accumulation into per-row partials
#pragma unroll
        for (int g = 0; g < 2; ++g) {
#pragma unroll
            for (int c = 0; c < 4; ++c) {
                int jl = g * 64 + 4 * tx + c;
                int j  = j0 + jl;
                float rj = rjs[jl];
                int   tj = tjs[jl];
                int   bj = bjs[jl];
#pragma unroll
                for (int r = 0; r < 4; ++r) {
                    int i = i0 + 4 * ty + r;
                    float raw = g ? s1[r][c] : s0[r][c];
                    float sv  = raw * (ri[r] * rj);
                    float et  = exp2f(sv * c1);
                    float eb  = exp2f(sv * c2);
                    bool nd = (i != j);
                    bool st = (tir[r] == tj) && nd;
                    bool sb = (bir[r] == bj);
                    aTT[r] += nd ? et : 0.0f;
                    aPT[r] += st ? et : 0.0f;
                    aTB[r] += st ? eb : 0.0f;
                    aPB[r] += (st && sb) ? eb : 0.0f;
                }
            }
        }
    }

    // reduce across tx (lane bits 0..3), then one atomic set per row from tx==0
#pragma unroll
    for (int r = 0; r < 4; ++r) {
#pragma unroll
        for (int m = 1; m < 16; m <<= 1) {
            aPT[r] += __shfl_xor(aPT[r], m, 64);
            aTT[r] += __shfl_xor(aTT[r], m, 64);
            aPB[r] += __shfl_xor(aPB[r], m, 64);
            aTB[r] += __shfl_xor(aTB[r], m, 64);
        }
    }
    if (tx == 0) {
#pragma unroll
        for (int r = 0; r < 4; ++r) {
            int i = i0 + 4 * ty + r;
            atomicAdd(&rowPosT[i], aPT[r]);
            atomicAdd(&rowTotT[i], aTT[r]);
            atomicAdd(&rowPosB[i], aPB[r]);
            atomicAdd(&rowTotB[i], aTB[r]);
        }
    }
}

__global__ __launch_bounds__(256) void k_fin(const int* __restrict__ tg,
                                             const int* __restrict__ bt,
                                             float* __restrict__ ws) {
    int i = blockIdx.x * 256 + threadIdx.x;
    if (i >= NN) return;
    float pt = ws[NN + i], tt = ws[2 * NN + i];
    float pb = ws[3 * NN + i], tb = ws[4 * NN + i];
    int ti = tg[i], bi = bt[i];
    const int* ip = (const int*)(ws + 5 * NN + 50);
    int cp  = ip[ti];
    int cpb = ip[NCLS + ti * NBATCH + bi];
    float* lsum_t = ws + 5 * NN;
    float* cnt_t  = lsum_t + 20;
    float* lsum_b = lsum_t + 40;
    float* cnt_b  = lsum_t + 45;
    if (cp >= 2 && (NN - cp) >= 1) {
        float neg  = tt - pt;                 // sum over !same_t (diag excluded)
        float loss = -logf(pt / (pt + neg));
        atomicAdd(&lsum_t[ti], loss);
        atomicAdd(&cnt_t[ti], 1.0f);
    }
    if (cpb >= 2 && (cp - cpb) >= 1) {
        float negb = tb - pb;                 // same_t & !same_b
        float lb   = -logf(pb / (pb + negb));
        atomicAdd(&lsum_b[bi], 1.0f / lb);
        atomicAdd(&cnt_b[bi], 1.0f);
    }
}

__global__ void k_out(const float* __restrict__ wt, const float* __restrict__ wb,
                      const float* __restrict__ ws, float* __restrict__ out) {
    if (threadIdx.x == 0 && blockIdx.x == 0) {
        const float* lsum_t = ws + 5 * NN;
        const float* cnt_t  = lsum_t + 20;
        const float* lsum_b = lsum_t + 40;
        const float* cnt_b  = lsum_t + 45;
        float lt = 0.0f, lb = 0.0f;
        for (int c = 0; c < NCLS; ++c) {
            float cc = cnt_t[c];
            if (cc > 0.0f) lt += (lsum_t[c] / fmaxf(cc, 1.0f)) * wt[c];
        }
        for (int b = 0; b < NBATCH; ++b) {
            float cc = cnt_b[b];
            if (cc > 0.0f) lb += (lsum_b[b] / fmaxf(cc, 1.0f)) * wb[b];
        }
        out[0] = 0.9f * lt + 0.1f * lb;
    }
}

extern "C" void kernel_launch(void* const* d_in, const int* in_sizes, int n_in,
                              void* d_out, int out_size, void* d_ws, size_t ws_size,
                              hipStream_t stream) {
    const float* x    = (const float*)d_in[0];
    const float* temp = (const float*)d_in[1];
    const float* wt   = (const float*)d_in[2];
    const float* wb   = (const float*)d_in[3];
    const int*   tg   = (const int*)d_in[4];
    const int*   bt   = (const int*)d_in[5];
    float* out = (float*)d_out;
    float* ws = (float*)d_ws;

    k_init<<<(4 * NN + 170 + 255) / 256, 256, 0, stream>>>(ws);
    k_prep<<<NN / 4, 256, 0, stream>>>(x, tg, bt, ws);
    dim3 grid(NN / 64, 8);
    k_main<<<grid, 256, 0, stream>>>(x, temp, tg, bt, ws);
    k_fin<<<(NN + 255) / 256, 256, 0, stream>>>(tg, bt, ws);
    k_out<<<1, 64, 0, stream>>>(wt, wb, ws, out);
}

// Round 3
// 174.633 us; speedup vs baseline: 2.0361x; 2.0361x over previous
//
#include <hip/hip_runtime.h>
#include <hip/hip_bf16.h>
#include <math.h>

#define NN 6144
#define DD 128
#define NCLS 20
#define NBATCH 5
#define NB 48                      // 6144 / 128 blocks per dim
#define NPAIR (NB * (NB + 1) / 2)  // 1176 upper-tri block pairs

typedef float f32x4 __attribute__((ext_vector_type(4)));
typedef short bf16x8 __attribute__((ext_vector_type(8)));

// ws layout:
//   ushort xnb[NN*DD]        bytes [0, 1572864)   normalized rows, bf16
//   float  stats[4*NN]       float index SOFF:  PT | TT | PB | TB
//   int    hist[120]         float index HOFF:  classCnt[20], pairCnt[20*5]
#define SOFF (NN * DD / 2)
#define HOFF (SOFF + 4 * NN)

// Block 0: class/(class,batch) histograms via LDS. Blocks 1..24: zero stats.
__global__ __launch_bounds__(1024) void k_zero(const int* __restrict__ tg,
                                               const int* __restrict__ bt,
                                               float* __restrict__ ws) {
    const int t = threadIdx.x;
    if (blockIdx.x > 0) {
        ws[SOFF + (blockIdx.x - 1) * 1024 + t] = 0.0f;  // 24*1024 = 4*NN
        return;
    }
    __shared__ int h[NCLS + NCLS * NBATCH];
    if (t < NCLS + NCLS * NBATCH) h[t] = 0;
    __syncthreads();
    for (int i = t; i < NN; i += 1024) {
        int c = tg[i], b = bt[i];
        atomicAdd(&h[c], 1);
        atomicAdd(&h[NCLS + c * NBATCH + b], 1);
    }
    __syncthreads();
    int* hp = (int*)(ws + HOFF);
    if (t < NCLS + NCLS * NBATCH) hp[t] = h[t];
}

// rinv per row, write normalized bf16 rows. Block = 4 rows x 64 lanes.
__global__ __launch_bounds__(256) void k_prep(const float* __restrict__ x,
                                              float* __restrict__ ws) {
    const int t = threadIdx.x;
    const int lane = t & 63;
    const int row = blockIdx.x * 4 + (t >> 6);
    float2 v = *(const float2*)(x + row * DD + 2 * lane);
    float s = v.x * v.x + v.y * v.y;
#pragma unroll
    for (int m = 1; m < 64; m <<= 1) s += __shfl_xor(s, m, 64);
    float rinv = 1.0f / fmaxf(sqrtf(s), 1e-8f);
    __hip_bfloat16 h0 = __float2bfloat16(v.x * rinv);
    __hip_bfloat16 h1 = __float2bfloat16(v.y * rinv);
    ushort2 u;
    u.x = *(ushort*)&h0;
    u.y = *(ushort*)&h1;
    ushort* xnb = (ushort*)ws;
    *(ushort2*)(xnb + row * DD + 2 * lane) = u;
}

// 128x128 tile per block over upper-tri block pairs; 4 waves in 2x2, each wave
// 64x64 via 4x4 mfma_f32_16x16x32_bf16. K=128 staged in two 64-chunks.
__global__ __launch_bounds__(256) void k_main(const float* __restrict__ temp,
                                              const int* __restrict__ tg,
                                              const int* __restrict__ bt,
                                              float* __restrict__ ws) {
    __shared__ ushort tA[128][72];  // 64 bf16 + 8 pad -> 144 B row (9 granules)
    __shared__ ushort tB[128][72];
    __shared__ int tgA[128], btA[128], tgB[128], btB[128];

    const ushort* xnb = (const ushort*)ws;
    float* PT = ws + SOFF;
    float* TT = PT + NN;
    float* PB = PT + 2 * NN;
    float* TB = PT + 3 * NN;

    // decode blockIdx.x -> (bi <= bj)
    int bi = 0, rem = blockIdx.x;
    while (rem >= NB - bi) { rem -= NB - bi; ++bi; }
    const int bj = bi + rem;
    const int I = bi * 128, J = bj * 128;
    const bool isDiag = (bi == bj);

    const int t = threadIdx.x;
    const int w = t >> 6;
    const int lane = t & 63;
    const int tx16 = lane & 15;
    const int quad = lane >> 4;
    const int rowBase = (w >> 1) * 64;
    const int colBase = (w & 1) * 64;

    const float tc = fminf(fmaxf(temp[0], 0.1f), 1.0f);
    const float c1 = 1.4426950408889634f / tc;   // exp(s/t)   = 2^(s*c1)
    const float c2 = 2.8853900817779268f;        // exp(s/0.5) = 2^(s*c2)

    if (t < 128) { tgA[t] = tg[I + t]; btA[t] = bt[I + t]; }
    else { int u = t - 128; tgB[u] = tg[J + u]; btB[u] = bt[J + u]; }

    f32x4 acc[4][4];
#pragma unroll
    for (int mt = 0; mt < 4; ++mt)
#pragma unroll
        for (int nt = 0; nt < 4; ++nt) acc[mt][nt] = (f32x4){0.f, 0.f, 0.f, 0.f};

    for (int kc = 0; kc < 2; ++kc) {
        if (kc) __syncthreads();  // protect LDS reuse
        {   // stage 128 rows x 64 bf16 for both tiles; thread = (row r0, chunk ch)
            const int r0 = t >> 3, ch = t & 7;
            const ushort* gA = xnb + (I + r0) * DD + kc * 64 + ch * 8;
            const ushort* gB = xnb + (J + r0) * DD + kc * 64 + ch * 8;
#pragma unroll
            for (int it = 0; it < 4; ++it) {
                *(float4*)&tA[r0 + 32 * it][ch * 8] = *(const float4*)(gA + 32 * it * DD);
                *(float4*)&tB[r0 + 32 * it][ch * 8] = *(const float4*)(gB + 32 * it * DD);
            }
        }
        __syncthreads();
#pragma unroll
        for (int ks = 0; ks < 2; ++ks) {
            bf16x8 a[4], b[4];
            const int ko = ks * 32 + quad * 8;
#pragma unroll
            for (int mt = 0; mt < 4; ++mt)
                a[mt] = *(const bf16x8*)&tA[rowBase + 16 * mt + tx16][ko];
#pragma unroll
            for (int nt = 0; nt < 4; ++nt)
                b[nt] = *(const bf16x8*)&tB[colBase + 16 * nt + tx16][ko];
#pragma unroll
            for (int mt = 0; mt < 4; ++mt)
#pragma unroll
                for (int nt = 0; nt < 4; ++nt)
                    acc[mt][nt] = __builtin_amdgcn_mfma_f32_16x16x32_bf16(
                        a[mt], b[nt], acc[mt][nt], 0, 0, 0);
        }
    }

    // ---- epilogue: masked exp accumulation, rows (i-side) + cols (j-side) ----
    float rPT[4][4] = {{0}}, rTT[4][4] = {{0}}, rPB[4][4] = {{0}}, rTB[4][4] = {{0}};
    float cPT[4] = {0}, cTT[4] = {0}, cPB[4] = {0}, cTB[4] = {0};
    int tjv[4], bjv[4];
#pragma unroll
    for (int nt = 0; nt < 4; ++nt) {
        int jl = colBase + 16 * nt + tx16;
        tjv[nt] = tgB[jl];
        bjv[nt] = btB[jl];
    }

#pragma unroll
    for (int mt = 0; mt < 4; ++mt) {
#pragma unroll
        for (int p = 0; p < 4; ++p) {
            const int il = rowBase + 16 * mt + 4 * quad + p;
            const int ti = tgA[il];
            const int bi_ = btA[il];
#pragma unroll
            for (int nt = 0; nt < 4; ++nt) {
                const int jl = colBase + 16 * nt + tx16;
                float s = acc[mt][nt][p];
                float et = __builtin_amdgcn_exp2f(c1 * s);
                float eb = __builtin_amdgcn_exp2f(c2 * s);
                bool nd = !isDiag || (il != jl);
                bool st = (ti == tjv[nt]) && nd;
                bool sb = (bi_ == bjv[nt]);
                rTT[mt][p] += nd ? et : 0.f;
                rPT[mt][p] += st ? et : 0.f;
                rTB[mt][p] += st ? eb : 0.f;
                rPB[mt][p] += (st && sb) ? eb : 0.f;
                if (!isDiag) {
                    cTT[nt] += et;
                    cPT[nt] += st ? et : 0.f;
                    cTB[nt] += st ? eb : 0.f;
                    cPB[nt] += (st && sb) ? eb : 0.f;
                }
            }
        }
    }

    // rows: reduce over tx16 (lane bits 0-3), atomics from tx16==0
#pragma unroll
    for (int mt = 0; mt < 4; ++mt) {
#pragma unroll
        for (int p = 0; p < 4; ++p) {
            float vPT = rPT[mt][p], vTT = rTT[mt][p], vPB = rPB[mt][p], vTB = rTB[mt][p];
#pragma unroll
            for (int m = 1; m < 16; m <<= 1) {
                vPT += __shfl_xor(vPT, m, 64);
                vTT += __shfl_xor(vTT, m, 64);
                vPB += __shfl_xor(vPB, m, 64);
                vTB += __shfl_xor(vTB, m, 64);
            }
            if (tx16 == 0) {
                int gi = I + rowBase + 16 * mt + 4 * quad + p;
                atomicAdd(&PT[gi], vPT);
                atomicAdd(&TT[gi], vTT);
                atomicAdd(&PB[gi], vPB);
                atomicAdd(&TB[gi], vTB);
            }
        }
    }
    // cols (transpose side): reduce over quad (lane bits 4-5), atomics from quad==0
    if (!isDiag) {
#pragma unroll
        for (int nt = 0; nt < 4; ++nt) {
            float vPT = cPT[nt], vTT = cTT[nt], vPB = cPB[nt], vTB = cTB[nt];
#pragma unroll
            for (int m = 16; m < 64; m <<= 1) {
                vPT += __shfl_xor(vPT, m, 64);
                vTT += __shfl_xor(vTT, m, 64);
                vPB += __shfl_xor(vPB, m, 64);
                vTB += __shfl_xor(vTB, m, 64);
            }
            if (quad == 0) {
                int gj = J + colBase + 16 * nt + tx16;
                atomicAdd(&PT[gj], vPT);
                atomicAdd(&TT[gj], vTT);
                atomicAdd(&PB[gj], vPB);
                atomicAdd(&TB[gj], vTB);
            }
        }
    }
}

// per-row losses + class means + final weighted sum, one block
__global__ __launch_bounds__(1024) void k_fin(const int* __restrict__ tg,
                                              const int* __restrict__ bt,
                                              const float* __restrict__ wt,
                                              const float* __restrict__ wb,
                                              const float* __restrict__ ws,
                                              float* __restrict__ out) {
    __shared__ float ls_t[NCLS], ct_t[NCLS], ls_b[NBATCH], cb_b[NBATCH];
    const int t = threadIdx.x;
    if (t < NCLS) { ls_t[t] = 0.f; ct_t[t] = 0.f; }
    if (t < NBATCH) { ls_b[t] = 0.f; cb_b[t] = 0.f; }
    __syncthreads();
    const float* PT = ws + SOFF;
    const float* TT = PT + NN;
    const float* PB = PT + 2 * NN;
    const float* TB = PT + 3 * NN;
    const int* hp = (const int*)(ws + HOFF);
    for (int i = t; i < NN; i += 1024) {
        float pt = PT[i], tt = TT[i], pb = PB[i], tb = TB[i];
        int ti = tg[i], bi = bt[i];
        int cp = hp[ti];
        int cpb = hp[NCLS + ti * NBATCH + bi];
        if (cp >= 2 && (NN - cp) >= 1) {
            float loss = -logf(pt / (pt + (tt - pt)));
            atomicAdd(&ls_t[ti], loss);
            atomicAdd(&ct_t[ti], 1.f);
        }
        if (cpb >= 2 && (cp - cpb) >= 1) {
            float lb = -logf(pb / (pb + (tb - pb)));
            atomicAdd(&ls_b[bi], 1.f / lb);
            atomicAdd(&cb_b[bi], 1.f);
        }
    }
    __syncthreads();
    if (t == 0) {
        float lt = 0.f, lb = 0.f;
        for (int c = 0; c < NCLS; ++c)
            if (ct_t[c] > 0.f) lt += (ls_t[c] / ct_t[c]) * wt[c];
        for (int b = 0; b < NBATCH; ++b)
            if (cb_b[b] > 0.f) lb += (ls_b[b] / cb_b[b]) * wb[b];
        out[0] = 0.9f * lt + 0.1f * lb;
    }
}

extern "C" void kernel_launch(void* const* d_in, const int* in_sizes, int n_in,
                              void* d_out, int out_size, void* d_ws, size_t ws_size,
                              hipStream_t stream) {
    const float* x    = (const float*)d_in[0];
    const float* temp = (const float*)d_in[1];
    const float* wt   = (const float*)d_in[2];
    const float* wb   = (const float*)d_in[3];
    const int*   tg   = (const int*)d_in[4];
    const int*   bt   = (const int*)d_in[5];
    float* out = (float*)d_out;
    float* ws = (float*)d_ws;

    k_zero<<<25, 1024, 0, stream>>>(tg, bt, ws);
    k_prep<<<NN / 4, 256, 0, stream>>>(x, ws);
    k_main<<<NPAIR, 256, 0, stream>>>(temp, tg, bt, ws);
    k_fin<<<1, 1024, 0, stream>>>(tg, bt, wt, wb, ws, out);
}

// Round 4
// 123.060 us; speedup vs baseline: 2.8894x; 1.4191x over previous
//
#include <hip/hip_runtime.h>
#include <hip/hip_bf16.h>
#include <math.h>

#define NN 6144
#define DD 128
#define NCLS 20
#define NBATCH 5
#define NB 48                      // 6144 / 128 blocks per dim
#define NPAIR (NB * (NB + 1) / 2)  // 1176 upper-tri block pairs

typedef float f32x4 __attribute__((ext_vector_type(4)));
typedef short bf16x8 __attribute__((ext_vector_type(8)));

// ws layout:
//   ushort xnb[NN*DD]        bytes [0, 1572864)   normalized rows, bf16
//   float  stats[4*NN]       float index SOFF:  PT | TT | PB | TB
//   int    hist[120]         float index HOFF:  classCnt[20], pairCnt[20*5]
//   float  accum[50]         float index AOFF:  ls_t[20] ct_t[20] ls_b[5] cb_b[5]
#define SOFF (NN * DD / 2)
#define HOFF (SOFF + 4 * NN)
#define AOFF (HOFF + 120)

// Block 0: class/(class,batch) histograms via LDS + zero accum. Blocks 1..24: zero stats.
__global__ __launch_bounds__(1024) void k_zero(const int* __restrict__ tg,
                                               const int* __restrict__ bt,
                                               float* __restrict__ ws) {
    const int t = threadIdx.x;
    if (blockIdx.x > 0) {
        ws[SOFF + (blockIdx.x - 1) * 1024 + t] = 0.0f;  // 24*1024 = 4*NN
        return;
    }
    __shared__ int h[NCLS + NCLS * NBATCH];
    if (t < NCLS + NCLS * NBATCH) h[t] = 0;
    if (t < 50) ws[AOFF + t] = 0.0f;
    __syncthreads();
    for (int i = t; i < NN; i += 1024) {
        int c = tg[i], b = bt[i];
        atomicAdd(&h[c], 1);
        atomicAdd(&h[NCLS + c * NBATCH + b], 1);
    }
    __syncthreads();
    int* hp = (int*)(ws + HOFF);
    if (t < NCLS + NCLS * NBATCH) hp[t] = h[t];
}

// rinv per row, write normalized bf16 rows. Block = 4 rows x 64 lanes.
__global__ __launch_bounds__(256) void k_prep(const float* __restrict__ x,
                                              float* __restrict__ ws) {
    const int t = threadIdx.x;
    const int lane = t & 63;
    const int row = blockIdx.x * 4 + (t >> 6);
    float2 v = *(const float2*)(x + row * DD + 2 * lane);
    float s = v.x * v.x + v.y * v.y;
#pragma unroll
    for (int m = 1; m < 64; m <<= 1) s += __shfl_xor(s, m, 64);
    float rinv = 1.0f / fmaxf(sqrtf(s), 1e-8f);
    __hip_bfloat16 h0 = __float2bfloat16(v.x * rinv);
    __hip_bfloat16 h1 = __float2bfloat16(v.y * rinv);
    ushort2 u;
    u.x = *(ushort*)&h0;
    u.y = *(ushort*)&h1;
    ushort* xnb = (ushort*)ws;
    *(ushort2*)(xnb + row * DD + 2 * lane) = u;
}

// 128x128 tile per block over upper-tri block pairs; 4 waves in 2x2, each wave
// 64x64 via 4x4 mfma_f32_16x16x32_bf16. Streaming (register-light) epilogue:
// per-mt row stats -> shuffle reduce -> LDS atomic; col stats after; one
// coalesced global-atomic flush per block.
__global__ __launch_bounds__(256) void k_main(const float* __restrict__ temp,
                                              const int* __restrict__ tg,
                                              const int* __restrict__ bt,
                                              float* __restrict__ ws) {
    __shared__ ushort tA[128][72];  // 64 bf16 + 8 pad -> 144 B row
    __shared__ ushort tB[128][72];
    __shared__ int tgA[128], btA[128], tgB[128], btB[128];
    __shared__ float sStat[4][256];  // [stat][0..127 = rows, 128..255 = cols]

    const ushort* xnb = (const ushort*)ws;
    float* PT = ws + SOFF;
    float* TT = PT + NN;
    float* PB = PT + 2 * NN;
    float* TB = PT + 3 * NN;

    // decode blockIdx.x -> (bi <= bj)
    int bi = 0, rem = blockIdx.x;
    while (rem >= NB - bi) { rem -= NB - bi; ++bi; }
    const int bj = bi + rem;
    const int I = bi * 128, J = bj * 128;
    const bool isDiag = (bi == bj);

    const int t = threadIdx.x;
    const int w = t >> 6;
    const int lane = t & 63;
    const int tx16 = lane & 15;
    const int quad = lane >> 4;
    const int rowBase = (w >> 1) * 64;
    const int colBase = (w & 1) * 64;

    const float tc = fminf(fmaxf(temp[0], 0.1f), 1.0f);
    const float c1 = 1.4426950408889634f / tc;   // exp(s/t)   = 2^(s*c1)
    const float c2 = 2.8853900817779268f;        // exp(s/0.5) = 2^(s*c2)

    if (t < 128) { tgA[t] = tg[I + t]; btA[t] = bt[I + t]; }
    else { int u = t - 128; tgB[u] = tg[J + u]; btB[u] = bt[J + u]; }
#pragma unroll
    for (int s = 0; s < 4; ++s) sStat[s][t] = 0.0f;

    f32x4 acc[4][4];
#pragma unroll
    for (int mt = 0; mt < 4; ++mt)
#pragma unroll
        for (int nt = 0; nt < 4; ++nt) acc[mt][nt] = (f32x4){0.f, 0.f, 0.f, 0.f};

    for (int kc = 0; kc < 2; ++kc) {
        if (kc) __syncthreads();
        {   // stage 128 rows x 64 bf16 for both tiles
            const int r0 = t >> 3, ch = t & 7;
            const ushort* gA = xnb + (I + r0) * DD + kc * 64 + ch * 8;
            const ushort* gB = xnb + (J + r0) * DD + kc * 64 + ch * 8;
#pragma unroll
            for (int it = 0; it < 4; ++it) {
                *(float4*)&tA[r0 + 32 * it][ch * 8] = *(const float4*)(gA + 32 * it * DD);
                *(float4*)&tB[r0 + 32 * it][ch * 8] = *(const float4*)(gB + 32 * it * DD);
            }
        }
        __syncthreads();
#pragma unroll
        for (int ks = 0; ks < 2; ++ks) {
            bf16x8 a[4], b[4];
            const int ko = ks * 32 + quad * 8;
#pragma unroll
            for (int mt = 0; mt < 4; ++mt)
                a[mt] = *(const bf16x8*)&tA[rowBase + 16 * mt + tx16][ko];
#pragma unroll
            for (int nt = 0; nt < 4; ++nt)
                b[nt] = *(const bf16x8*)&tB[colBase + 16 * nt + tx16][ko];
#pragma unroll
            for (int mt = 0; mt < 4; ++mt)
#pragma unroll
                for (int nt = 0; nt < 4; ++nt)
                    acc[mt][nt] = __builtin_amdgcn_mfma_f32_16x16x32_bf16(
                        a[mt], b[nt], acc[mt][nt], 0, 0, 0);
        }
    }

    // ---- streaming epilogue ----
    float cPT[4] = {0}, cTT[4] = {0}, cPB[4] = {0}, cTB[4] = {0};
    int tjv[4], bjv[4];
#pragma unroll
    for (int nt = 0; nt < 4; ++nt) {
        int jl = colBase + 16 * nt + tx16;
        tjv[nt] = tgB[jl];
        bjv[nt] = btB[jl];
    }

#pragma unroll
    for (int mt = 0; mt < 4; ++mt) {
        float rPT[4] = {0}, rTT[4] = {0}, rPB[4] = {0}, rTB[4] = {0};
        int til[4], bil[4];
#pragma unroll
        for (int p = 0; p < 4; ++p) {
            int il = rowBase + 16 * mt + 4 * quad + p;
            til[p] = tgA[il];
            bil[p] = btA[il];
        }
#pragma unroll
        for (int nt = 0; nt < 4; ++nt) {
            const int jl = colBase + 16 * nt + tx16;
#pragma unroll
            for (int p = 0; p < 4; ++p) {
                const int il = rowBase + 16 * mt + 4 * quad + p;
                float s = acc[mt][nt][p];
                float et = __builtin_amdgcn_exp2f(c1 * s);
                float eb = __builtin_amdgcn_exp2f(c2 * s);
                bool nd = !isDiag || (il != jl);
                bool st = (til[p] == tjv[nt]) && nd;
                bool sb = (bil[p] == bjv[nt]);
                rTT[p] += nd ? et : 0.f;
                rPT[p] += st ? et : 0.f;
                rTB[p] += st ? eb : 0.f;
                rPB[p] += (st && sb) ? eb : 0.f;
                if (!isDiag) {
                    cTT[nt] += et;
                    cPT[nt] += st ? et : 0.f;
                    cTB[nt] += st ? eb : 0.f;
                    cPB[nt] += (st && sb) ? eb : 0.f;
                }
            }
        }
        // reduce row stats over tx16 (lane bits 0-3), LDS-atomic from tx16==0
#pragma unroll
        for (int p = 0; p < 4; ++p) {
            float vPT = rPT[p], vTT = rTT[p], vPB = rPB[p], vTB = rTB[p];
#pragma unroll
            for (int m = 1; m < 16; m <<= 1) {
                vPT += __shfl_xor(vPT, m, 64);
                vTT += __shfl_xor(vTT, m, 64);
                vPB += __shfl_xor(vPB, m, 64);
                vTB += __shfl_xor(vTB, m, 64);
            }
            if (tx16 == 0) {
                int il = rowBase + 16 * mt + 4 * quad + p;
                atomicAdd(&sStat[0][il], vPT);
                atomicAdd(&sStat[1][il], vTT);
                atomicAdd(&sStat[2][il], vPB);
                atomicAdd(&sStat[3][il], vTB);
            }
        }
    }
    // cols: reduce over quad (lane bits 4-5), LDS-atomic from quad==0
    if (!isDiag) {
#pragma unroll
        for (int nt = 0; nt < 4; ++nt) {
            float vPT = cPT[nt], vTT = cTT[nt], vPB = cPB[nt], vTB = cTB[nt];
#pragma unroll
            for (int m = 16; m < 64; m <<= 1) {
                vPT += __shfl_xor(vPT, m, 64);
                vTT += __shfl_xor(vTT, m, 64);
                vPB += __shfl_xor(vPB, m, 64);
                vTB += __shfl_xor(vTB, m, 64);
            }
            if (quad == 0) {
                int cl = 128 + colBase + 16 * nt + tx16;
                atomicAdd(&sStat[0][cl], vPT);
                atomicAdd(&sStat[1][cl], vTT);
                atomicAdd(&sStat[2][cl], vPB);
                atomicAdd(&sStat[3][cl], vTB);
            }
        }
    }

    // coalesced global flush
    __syncthreads();
    if (t < 128) {
        int gi = I + t;
        atomicAdd(&PT[gi], sStat[0][t]);
        atomicAdd(&TT[gi], sStat[1][t]);
        atomicAdd(&PB[gi], sStat[2][t]);
        atomicAdd(&TB[gi], sStat[3][t]);
    } else if (!isDiag) {
        int gj = J + (t - 128);
        atomicAdd(&PT[gj], sStat[0][t]);
        atomicAdd(&TT[gj], sStat[1][t]);
        atomicAdd(&PB[gj], sStat[2][t]);
        atomicAdd(&TB[gj], sStat[3][t]);
    }
}

// per-row losses -> per-class LDS partials -> global accumulators. 24 blocks.
__global__ __launch_bounds__(256) void k_fin(const int* __restrict__ tg,
                                             const int* __restrict__ bt,
                                             float* __restrict__ ws) {
    __shared__ float ls_t[NCLS], ct_t[NCLS], ls_b[NBATCH], cb_b[NBATCH];
    const int t = threadIdx.x;
    if (t < NCLS) { ls_t[t] = 0.f; ct_t[t] = 0.f; }
    if (t < NBATCH) { ls_b[t] = 0.f; cb_b[t] = 0.f; }
    __syncthreads();
    const float* PT = ws + SOFF;
    const float* TT = PT + NN;
    const float* PB = PT + 2 * NN;
    const float* TB = PT + 3 * NN;
    const int* hp = (const int*)(ws + HOFF);
    const int i = blockIdx.x * 256 + t;
    float pt = PT[i], tt = TT[i], pb = PB[i], tb = TB[i];
    int ti = tg[i], bi = bt[i];
    int cp = hp[ti];
    int cpb = hp[NCLS + ti * NBATCH + bi];
    if (cp >= 2 && (NN - cp) >= 1) {
        float loss = -logf(pt / (pt + (tt - pt)));
        atomicAdd(&ls_t[ti], loss);
        atomicAdd(&ct_t[ti], 1.f);
    }
    if (cpb >= 2 && (cp - cpb) >= 1) {
        float lb = -logf(pb / (pb + (tb - pb)));
        atomicAdd(&ls_b[bi], 1.f / lb);
        atomicAdd(&cb_b[bi], 1.f);
    }
    __syncthreads();
    float* acc = ws + AOFF;
    if (t < NCLS) {
        if (ls_t[t] != 0.f) atomicAdd(&acc[t], ls_t[t]);
        if (ct_t[t] != 0.f) atomicAdd(&acc[NCLS + t], ct_t[t]);
    }
    if (t < NBATCH) {
        if (ls_b[t] != 0.f) atomicAdd(&acc[2 * NCLS + t], ls_b[t]);
        if (cb_b[t] != 0.f) atomicAdd(&acc[2 * NCLS + NBATCH + t], cb_b[t]);
    }
}

__global__ void k_out(const float* __restrict__ wt, const float* __restrict__ wb,
                      const float* __restrict__ ws, float* __restrict__ out) {
    if (threadIdx.x == 0 && blockIdx.x == 0) {
        const float* acc = ws + AOFF;
        float lt = 0.f, lb = 0.f;
        for (int c = 0; c < NCLS; ++c)
            if (acc[NCLS + c] > 0.f) lt += (acc[c] / acc[NCLS + c]) * wt[c];
        for (int b = 0; b < NBATCH; ++b)
            if (acc[2 * NCLS + NBATCH + b] > 0.f)
                lb += (acc[2 * NCLS + b] / acc[2 * NCLS + NBATCH + b]) * wb[b];
        out[0] = 0.9f * lt + 0.1f * lb;
    }
}

extern "C" void kernel_launch(void* const* d_in, const int* in_sizes, int n_in,
                              void* d_out, int out_size, void* d_ws, size_t ws_size,
                              hipStream_t stream) {
    const float* x    = (const float*)d_in[0];
    const float* temp = (const float*)d_in[1];
    const float* wt   = (const float*)d_in[2];
    const float* wb   = (const float*)d_in[3];
    const int*   tg   = (const int*)d_in[4];
    const int*   bt   = (const int*)d_in[5];
    float* out = (float*)d_out;
    float* ws = (float*)d_ws;

    k_zero<<<25, 1024, 0, stream>>>(tg, bt, ws);
    k_prep<<<NN / 4, 256, 0, stream>>>(x, ws);
    k_main<<<NPAIR, 256, 0, stream>>>(temp, tg, bt, ws);
    k_fin<<<NN / 256, 256, 0, stream>>>(tg, bt, ws);
    k_out<<<1, 64, 0, stream>>>(wt, wb, ws, out);
}